// Round 10
// baseline (221.486 us; speedup 1.0000x reference)
//
#include <hip/hip_runtime.h>
#include <math.h>

#define BB 4
#define HH 8
#define LL 2048
#define DD 64
#define SK 40            // sample_k == u == 40 for L=2048, FACTOR=5
#define BH (BB*HH)       // 32
#define NG 10            // stage-3 query groups of 4 (descending length)
#define QB 128           // queries per stage1-M block
#define NT 16            // K tiles
#define TR 128           // rows per tile
#define KPAD 17          // float4 stride per LDS tile row (pad vs 16)

__device__ __forceinline__ unsigned ordu(float v) {
    unsigned u = __float_as_uint(v);
    return (u & 0x80000000u) ? ~u : (u | 0x80000000u);
}

__device__ __forceinline__ float dot4(float4 a, float4 b) {
    return a.x * b.x + a.y * b.y + a.z * b.z + a.w * b.w;
}

// ---------------------------------------------------------------------------
// Stage 1: blocks [0,512) compute M via LDS-staged K tiles (no L2 gather);
// blocks [512,1024) compute V chunk sums.
__global__ __launch_bounds__(256) void stage1_kernel(
        const float* __restrict__ Q, const float* __restrict__ K,
        const float* __restrict__ V, const int* __restrict__ IDX,
        float* __restrict__ M, float* __restrict__ csum) {
    int tid = threadIdx.x;
    if (blockIdx.x < 512) {
        int x = blockIdx.x;
        int bhLo = x & 7;
        int r = x >> 3;                   // [0,64)
        int bhHi = r & 3;
        int qc = r >> 2;                  // [0,16)
        int bh = bhHi * 8 + bhLo;
        int qbase = qc * QB;

        __shared__ float4 ktile[TR * KPAD];            // 34.8 KB
        __shared__ unsigned short sorted[QB][SK];      // 10 KB
        __shared__ unsigned short starts[QB][NT + 1];  // 4.4 KB

        // 1. stage raw sample indices into the (not-yet-used) ktile area
        int* raw = (int*)ktile;           // 5120 ints = 20 KB < 34.8 KB
        for (int i = tid; i < QB * SK; i += 256) raw[i] = IDX[(size_t)qbase * SK + i];
        __syncthreads();

        // 2. per-query counting sort by tile (threads 0..127)
        if (tid < QB) {
            int pos = 0;
            const int* myraw = raw + tid * SK;
            for (int t = 0; t < NT; ++t) {
                starts[tid][t] = (unsigned short)pos;
                for (int s = 0; s < SK; ++s) {
                    int ks = myraw[s];
                    if ((ks >> 7) == t) sorted[tid][pos++] = (unsigned short)ks;
                }
            }
            starts[tid][NT] = (unsigned short)pos;   // == SK
        }

        // 3. query registers: 4 lanes/query, each group owns q0=g and q1=g+64
        int g = tid >> 2, c = tid & 3;
        int q0 = qbase + g, q1 = qbase + g + 64;
        const float4* Q4 = (const float4*)Q;
        const float4* K4 = (const float4*)K;
        float4 qa[4], qb[4];
        #pragma unroll
        for (int j = 0; j < 4; ++j) {
            qa[j] = Q4[((size_t)bh * LL + q0) * 16 + j * 4 + c];
            qb[j] = Q4[((size_t)bh * LL + q1) * 16 + j * 4 + c];
        }

        size_t kb4 = (size_t)bh * LL * 16;
        float mxa = -INFINITY, sma = 0.f, mxb = -INFINITY, smb = 0.f;

        for (int kt = 0; kt < NT; ++kt) {
            __syncthreads();   // kt=0: sort done (raw free); else: prev tile done
            // stage tile kt coalesced: 2048 float4s, 8 per thread
            #pragma unroll
            for (int i = 0; i < 8; ++i) {
                int f = tid + i * 256;
                int row = f >> 4, ch = f & 15;
                ktile[row * KPAD + ch] = K4[kb4 + (size_t)(kt * TR + row) * 16 + ch];
            }
            __syncthreads();
            // process q0's slice in this tile
            int s0 = starts[g][kt], s1 = starts[g][kt + 1];
            for (int s = s0; s < s1; ++s) {
                int rowi = sorted[g][s] & (TR - 1);
                const float4* kr = ktile + rowi * KPAD;
                float p = dot4(kr[c], qa[0]) + dot4(kr[4 + c], qa[1])
                        + dot4(kr[8 + c], qa[2]) + dot4(kr[12 + c], qa[3]);
                p += __shfl_xor(p, 1, 64);
                p += __shfl_xor(p, 2, 64);
                mxa = fmaxf(mxa, p); sma += p;
            }
            // process q1's slice
            int t0 = starts[g + 64][kt], t1 = starts[g + 64][kt + 1];
            for (int s = t0; s < t1; ++s) {
                int rowi = sorted[g + 64][s] & (TR - 1);
                const float4* kr = ktile + rowi * KPAD;
                float p = dot4(kr[c], qb[0]) + dot4(kr[4 + c], qb[1])
                        + dot4(kr[8 + c], qb[2]) + dot4(kr[12 + c], qb[3]);
                p += __shfl_xor(p, 1, 64);
                p += __shfl_xor(p, 2, 64);
                mxb = fmaxf(mxb, p); smb += p;
            }
        }
        if (c == 0) {
            M[(size_t)bh * LL + q0] = mxa - sma * (1.0f / (float)LL);
            M[(size_t)bh * LL + q1] = mxb - smb * (1.0f / (float)LL);
        }
    } else {
        // ----- vsum: per-(bh,chunk-of-128) column sums of V
        int x = blockIdx.x - 512;         // [0,512)
        int bhLo = x & 7, r = x >> 3;
        int bhHi = r & 3, c = r >> 2;     // c in [0,16)
        int bh = bhHi * 8 + bhLo;
        int d = tid & 63, sg = tid >> 6;
        size_t base = (size_t)bh * LL * DD;
        int row0 = c * 128 + sg * 32;
        float s = 0.f;
        for (int j = 0; j < 32; ++j) s += V[base + (size_t)(row0 + j) * DD + d];
        __shared__ float part[4][DD];
        part[sg][d] = s;
        __syncthreads();
        if (sg == 0)
            csum[((size_t)bh * 16 + c) * DD + d] = part[0][d] + part[1][d] + part[2][d] + part[3][d];
    }
}

// ---------------------------------------------------------------------------
// Stage 2: blocks [0,512) cumsum V -> out; blocks [512,544) radix top-40 of M,
// emitted DESCENDING by qpos (stage-3 groups need similar lengths).
__global__ __launch_bounds__(256) void stage2_kernel(
        const float* __restrict__ V, const float* __restrict__ csum,
        const float* __restrict__ M, float* __restrict__ out,
        int* __restrict__ topk) {
    int tid = threadIdx.x;
    if (blockIdx.x < 512) {
        // ----- cumsum
        int x = blockIdx.x;
        int bhLo = x & 7, r = x >> 3;
        int bhHi = r & 3, c = r >> 2;
        int bh = bhHi * 8 + bhLo;
        int d = tid & 63, sg = tid >> 6;
        size_t base = (size_t)bh * LL * DD;
        int row0 = c * 128 + sg * 32;
        float v[32];
        #pragma unroll
        for (int j = 0; j < 32; ++j) v[j] = V[base + (size_t)(row0 + j) * DD + d];
        float s = 0.f;
        #pragma unroll
        for (int j = 0; j < 32; ++j) s += v[j];
        __shared__ float part[4][DD];
        part[sg][d] = s;
        __syncthreads();
        float pre = 0.f;
        for (int cc = 0; cc < c; ++cc) pre += csum[((size_t)bh * 16 + cc) * DD + d];
        for (int ss = 0; ss < sg; ++ss) pre += part[ss][d];
        float acc = pre;
        #pragma unroll
        for (int j = 0; j < 32; ++j) {
            acc += v[j];
            out[base + (size_t)(row0 + j) * DD + d] = acc;
        }
    } else {
        // ----- radix top-40 (8 bits/pass, 4 passes); then sort desc by index.
        int bh = blockIdx.x - 512;
        __shared__ unsigned hist[256];
        __shared__ unsigned bc_prefix, bc_need;
        __shared__ unsigned cnt_gt, cnt_eq;
        __shared__ int eqlist[128];
        __shared__ int sel[SK];

        unsigned v[8];
        #pragma unroll
        for (int j = 0; j < 8; ++j)
            v[j] = ordu(M[(size_t)bh * LL + tid + j * 256]);

        unsigned prefix = 0, need = SK;
        #pragma unroll
        for (int pass = 0; pass < 4; ++pass) {
            const int s = 24 - 8 * pass;
            const unsigned maskHigh = (pass == 0) ? 0u : (0xFFFFFFFFu << (s + 8));
            hist[tid] = 0;
            __syncthreads();
            #pragma unroll
            for (int j = 0; j < 8; ++j)
                if (((v[j] ^ prefix) & maskHigh) == 0)
                    atomicAdd(&hist[(v[j] >> s) & 0xFF], 1u);
            __syncthreads();
            unsigned above = 0;
            for (int b = tid + 1; b < 256; ++b) above += hist[b];
            if (above < need && above + hist[tid] >= need) {
                bc_prefix = prefix | ((unsigned)tid << s);
                bc_need = need - above;
            }
            __syncthreads();
            prefix = bc_prefix;
            need = bc_need;
            __syncthreads();
        }
        unsigned T = prefix;
        if (tid == 0) { cnt_gt = 0; cnt_eq = 0; }
        __syncthreads();
        #pragma unroll
        for (int j = 0; j < 8; ++j) {
            int idx = tid + j * 256;
            if (v[j] > T) { unsigned p = atomicAdd(&cnt_gt, 1u); sel[p] = idx; }
            else if (v[j] == T) { unsigned p = atomicAdd(&cnt_eq, 1u); if (p < 128) eqlist[p] = idx; }
        }
        __syncthreads();
        if (tid == 0) {
            int ne = (int)min(cnt_eq, 128u);
            unsigned base = cnt_gt;       // == SK - need
            for (unsigned r2 = 0; r2 < need; ++r2) {
                int bj = 0, bv = 0x7FFFFFFF;
                for (int j = 0; j < ne; ++j)
                    if (eqlist[j] < bv) { bv = eqlist[j]; bj = j; }
                sel[base + r2] = bv;
                eqlist[bj] = 0x7FFFFFFF;
            }
        }
        __syncthreads();
        // rank-sort descending by qpos (indices distinct): longest rows first
        if (tid < SK) {
            int mine = sel[tid];
            int rank = 0;
            #pragma unroll
            for (int j = 0; j < SK; ++j) rank += (sel[j] > mine);
            topk[bh * SK + rank] = mine;
        }
    }
}

// ---------------------------------------------------------------------------
// Stage 3: one block per (bh, group of 4 sorted u's). Each K/V row load feeds
// 4 queries. Two-pass softmax per query over sc[4][nk] in LDS.
__global__ __launch_bounds__(256) void attn_kernel(
        const float* __restrict__ Q, const float* __restrict__ K,
        const float* __restrict__ V, const int* __restrict__ topk,
        float* __restrict__ out) {
    int x = blockIdx.x;               // 320
    int bh = x & 31;                  // XCD spread; same-bh groups same XCD
    int g = x >> 5;                   // [0,10), ascending = longest-first
    int tid = threadIdx.x;

    int qp[4];
    #pragma unroll
    for (int i = 0; i < 4; ++i) qp[i] = topk[bh * SK + g * 4 + i];
    int nk = qp[0] + 1;               // descending within group -> qp[0] max

    const float4* Q4 = (const float4*)Q;
    const float4* K4 = (const float4*)K;
    const float4* V4 = (const float4*)V;

    int w = tid >> 6, lane = tid & 63;
    int c = lane & 3, kw = lane >> 2; // 4 lanes/key, 16 keys/wave-round

    float4 qreg[4][4];
    #pragma unroll
    for (int i = 0; i < 4; ++i)
        #pragma unroll
        for (int j = 0; j < 4; ++j)
            qreg[i][j] = Q4[((size_t)bh * LL + qp[i]) * 16 + j * 4 + c];

    __shared__ float sc[4][LL];       // 32 KB
    __shared__ float red[4][4], red2[4][4];
    __shared__ float opart[16][16][4];

    // ---- score phase: 64 keys per block-round, 4 dots per row load
    size_t kb4 = (size_t)bh * LL * 16;
    int rounds = (nk + 63) >> 6;
    for (int rr = 0; rr < rounds; ++rr) {
        int key = rr * 64 + w * 16 + kw;
        if (key < nk) {
            float4 A[4];
            #pragma unroll
            for (int j = 0; j < 4; ++j) A[j] = K4[kb4 + (size_t)key * 16 + j * 4 + c];
            float p0 = 0.f, p1 = 0.f, p2 = 0.f, p3 = 0.f;
            #pragma unroll
            for (int j = 0; j < 4; ++j) {
                p0 += dot4(A[j], qreg[0][j]);
                p1 += dot4(A[j], qreg[1][j]);
                p2 += dot4(A[j], qreg[2][j]);
                p3 += dot4(A[j], qreg[3][j]);
            }
            p0 += __shfl_xor(p0, 1, 64); p0 += __shfl_xor(p0, 2, 64);
            p1 += __shfl_xor(p1, 1, 64); p1 += __shfl_xor(p1, 2, 64);
            p2 += __shfl_xor(p2, 1, 64); p2 += __shfl_xor(p2, 2, 64);
            p3 += __shfl_xor(p3, 1, 64); p3 += __shfl_xor(p3, 2, 64);
            if (c == 0) {
                sc[0][key] = (key <= qp[0]) ? p0 * 0.125f : -INFINITY;
                sc[1][key] = (key <= qp[1]) ? p1 * 0.125f : -INFINITY;
                sc[2][key] = (key <= qp[2]) ? p2 * 0.125f : -INFINITY;
                sc[3][key] = (key <= qp[3]) ? p3 * 0.125f : -INFINITY;
            }
        }
    }
    __syncthreads();

    // ---- max per query
    float m[4] = {-INFINITY, -INFINITY, -INFINITY, -INFINITY};
    for (int j = tid; j < nk; j += 256) {
        #pragma unroll
        for (int i = 0; i < 4; ++i) m[i] = fmaxf(m[i], sc[i][j]);
    }
    #pragma unroll
    for (int i = 0; i < 4; ++i) {
        float mv = m[i];
        #pragma unroll
        for (int off = 32; off > 0; off >>= 1) mv = fmaxf(mv, __shfl_xor(mv, off, 64));
        if (lane == 0) red[w][i] = mv;
    }
    __syncthreads();
    #pragma unroll
    for (int i = 0; i < 4; ++i)
        m[i] = fmaxf(fmaxf(red[0][i], red[1][i]), fmaxf(red[2][i], red[3][i]));

    // ---- exp + sum per query
    float l[4] = {0.f, 0.f, 0.f, 0.f};
    for (int j = tid; j < nk; j += 256) {
        #pragma unroll
        for (int i = 0; i < 4; ++i) {
            float e = expf(sc[i][j] - m[i]);   // -inf -> 0
            sc[i][j] = e;
            l[i] += e;
        }
    }
    #pragma unroll
    for (int i = 0; i < 4; ++i) {
        float lv = l[i];
        #pragma unroll
        for (int off = 32; off > 0; off >>= 1) lv += __shfl_xor(lv, off, 64);
        if (lane == 0) red2[w][i] = lv;
    }
    __syncthreads();
    float linv[4];
    #pragma unroll
    for (int i = 0; i < 4; ++i)
        linv[i] = 1.0f / (red2[0][i] + red2[1][i] + red2[2][i] + red2[3][i]);

    // ---- PV: each V row load feeds 4 accumulators
    int col4 = tid & 15, kg = tid >> 4;
    float4 acc[4];
    #pragma unroll
    for (int i = 0; i < 4; ++i) acc[i] = make_float4(0.f, 0.f, 0.f, 0.f);
    size_t vb4 = (size_t)bh * LL * 16;
    for (int j = kg; j < nk; j += 16) {
        float4 vv = V4[vb4 + (size_t)j * 16 + col4];
        #pragma unroll
        for (int i = 0; i < 4; ++i) {
            float sj = sc[i][j];
            acc[i].x += sj * vv.x; acc[i].y += sj * vv.y;
            acc[i].z += sj * vv.z; acc[i].w += sj * vv.w;
        }
    }
    #pragma unroll
    for (int i = 0; i < 4; ++i) {
        opart[kg][col4][0] = acc[i].x;
        opart[kg][col4][1] = acc[i].y;
        opart[kg][col4][2] = acc[i].z;
        opart[kg][col4][3] = acc[i].w;
        __syncthreads();
        if (tid < DD) {
            int c4 = tid >> 2, cp = tid & 3;
            float s = 0.f;
            #pragma unroll
            for (int kg2 = 0; kg2 < 16; ++kg2) s += opart[kg2][c4][cp];
            out[((size_t)bh * LL + qp[i]) * DD + tid] = s * linv[i];
        }
        __syncthreads();
    }
}

// ---------------------------------------------------------------------------
extern "C" void kernel_launch(void* const* d_in, const int* in_sizes, int n_in,
                              void* d_out, int out_size, void* d_ws, size_t ws_size,
                              hipStream_t stream) {
    const float* Q   = (const float*)d_in[0];
    const float* K   = (const float*)d_in[1];
    const float* V   = (const float*)d_in[2];
    const int*   IDX = (const int*)d_in[3];
    float* out = (float*)d_out;

    char* ws = (char*)d_ws;
    float* M    = (float*)ws;  ws += (size_t)BH * LL * sizeof(float);                 // 256 KB
    int*   topk = (int*)ws;    ws += ((size_t)BH * SK * sizeof(int) + 255) & ~255ull;
    float* csum = (float*)ws;  // BH*16*DD floats = 128 KB

    stage1_kernel<<<1024, 256, 0, stream>>>(Q, K, V, IDX, M, csum);
    stage2_kernel<<<544, 256, 0, stream>>>(V, csum, M, out, topk);
    attn_kernel<<<BH * NG, 256, 0, stream>>>(Q, K, V, topk, out);
}

// Round 11
// 166.748 us; speedup vs baseline: 1.3283x; 1.3283x over previous
//
#include <hip/hip_runtime.h>
#include <math.h>

#define BB 4
#define HH 8
#define LL 2048
#define DD 64
#define SK 40            // sample_k == u == 40 for L=2048, FACTOR=5
#define BH (BB*HH)       // 32
#define NC 32            // cumsum chunks per bh (64 rows each)

__device__ __forceinline__ unsigned ordu(float v) {
    unsigned u = __float_as_uint(v);
    return (u & 0x80000000u) ? ~u : (u | 0x80000000u);
}

__device__ __forceinline__ float dot4(float4 a, float4 b) {
    return a.x * b.x + a.y * b.y + a.z * b.z + a.w * b.w;
}

// ---------------------------------------------------------------------------
// Stage 1: blocks [0,1024) compute M (R6-proven simple gather, unroll 8);
// blocks [1024,2048) compute V 64-row chunk sums (float4 columns).
__global__ __launch_bounds__(256) void stage1_kernel(
        const float* __restrict__ Q, const float* __restrict__ K,
        const float* __restrict__ V, const int* __restrict__ IDX,
        float* __restrict__ M, float* __restrict__ csum) {
    int tid = threadIdx.x;
    __shared__ int sidx[64 * SK];         // 10 KB (M branch)
    __shared__ float4 part4[16][16];      // 4 KB (vsum branch)

    if (blockIdx.x < 1024) {
        // ----- compute_M: 4 lanes/query, 16 queries/wave, 64 queries/block
        int x = blockIdx.x;
        int bhLo = x & 7;
        int r = x >> 3;                   // [0,128)
        int bhHi = r & 3;
        int chunk = r >> 2;               // [0,32)
        int bh = bhHi * 8 + bhLo;
        int qbase = chunk * 64;
        int w = tid >> 6, lane = tid & 63;
        int qw = lane >> 2, c = lane & 3;
        int qi = w * 16 + qw;
        int qpos = qbase + qi;

        for (int i = tid; i < 64 * SK; i += 256) sidx[i] = IDX[(size_t)qbase * SK + i];

        const float4* Q4 = (const float4*)Q;
        const float4* K4 = (const float4*)K;
        float4 qreg[4];
        #pragma unroll
        for (int j = 0; j < 4; ++j)
            qreg[j] = Q4[((size_t)bh * LL + qpos) * 16 + j * 4 + c];
        __syncthreads();

        size_t kb4 = (size_t)bh * LL * 16;
        float mx = -INFINITY, sm = 0.f;
        #pragma unroll 8
        for (int s = 0; s < SK; ++s) {
            int ks = sidx[qi * SK + s];
            const float4* kr = K4 + kb4 + (size_t)ks * 16;
            float p = dot4(kr[c], qreg[0]) + dot4(kr[4 + c], qreg[1])
                    + dot4(kr[8 + c], qreg[2]) + dot4(kr[12 + c], qreg[3]);
            p += __shfl_xor(p, 1, 64);
            p += __shfl_xor(p, 2, 64);
            mx = fmaxf(mx, p);
            sm += p;
        }
        if (c == 0) M[(size_t)bh * LL + qpos] = mx - sm * (1.0f / (float)LL);
    } else {
        // ----- vsum: (bh, chunk of 64 rows) -> csum4[bh][chunk][16] (float4)
        int x = blockIdx.x - 1024;        // [0,1024)
        int bhLo = x & 7, r = x >> 3;     // r in [0,128)
        int bhHi = r & 3, c = r >> 2;     // c in [0,32)
        int bh = bhHi * 8 + bhLo;
        int col4 = tid & 15, sg = tid >> 4;   // sg in [0,16): 4 rows each
        const float4* V4 = (const float4*)V;
        size_t vb4 = (size_t)bh * LL * 16;
        int row0 = c * 64 + sg * 4;
        float4 s = make_float4(0.f, 0.f, 0.f, 0.f);
        #pragma unroll
        for (int j = 0; j < 4; ++j) {
            float4 v = V4[vb4 + (size_t)(row0 + j) * 16 + col4];
            s.x += v.x; s.y += v.y; s.z += v.z; s.w += v.w;
        }
        part4[sg][col4] = s;
        __syncthreads();
        if (tid < 16) {
            float4 t = part4[0][tid];
            #pragma unroll
            for (int ss = 1; ss < 16; ++ss) {
                float4 p = part4[ss][tid];
                t.x += p.x; t.y += p.y; t.z += p.z; t.w += p.w;
            }
            ((float4*)csum)[((size_t)bh * NC + c) * 16 + tid] = t;
        }
    }
}

// ---------------------------------------------------------------------------
// Stage 2: blocks [0,1024) cumsum V -> out (float4, 64-row chunks);
// blocks [1024,1056) radix top-40 of M, emitted DESCENDING by qpos.
__global__ __launch_bounds__(256) void stage2_kernel(
        const float* __restrict__ V, const float* __restrict__ csum,
        const float* __restrict__ M, float* __restrict__ out,
        int* __restrict__ topk) {
    int tid = threadIdx.x;
    if (blockIdx.x < 1024) {
        // ----- cumsum
        int x = blockIdx.x;
        int bhLo = x & 7, r = x >> 3;
        int bhHi = r & 3, c = r >> 2;     // c in [0,32)
        int bh = bhHi * 8 + bhLo;
        int col4 = tid & 15, sg = tid >> 4;
        const float4* V4 = (const float4*)V;
        const float4* C4 = (const float4*)csum;
        float4* O4 = (float4*)out;
        size_t vb4 = (size_t)bh * LL * 16;
        int row0 = c * 64 + sg * 4;

        float4 v[4];
        #pragma unroll
        for (int j = 0; j < 4; ++j)
            v[j] = V4[vb4 + (size_t)(row0 + j) * 16 + col4];

        __shared__ float4 part4[16][16];
        float4 s = make_float4(v[0].x + v[1].x + v[2].x + v[3].x,
                               v[0].y + v[1].y + v[2].y + v[3].y,
                               v[0].z + v[1].z + v[2].z + v[3].z,
                               v[0].w + v[1].w + v[2].w + v[3].w);
        part4[sg][col4] = s;
        __syncthreads();

        float4 pre = make_float4(0.f, 0.f, 0.f, 0.f);
        for (int cc = 0; cc < c; ++cc) {
            float4 p = C4[((size_t)bh * NC + cc) * 16 + col4];
            pre.x += p.x; pre.y += p.y; pre.z += p.z; pre.w += p.w;
        }
        for (int ss = 0; ss < sg; ++ss) {
            float4 p = part4[ss][col4];
            pre.x += p.x; pre.y += p.y; pre.z += p.z; pre.w += p.w;
        }
        float4 acc = pre;
        #pragma unroll
        for (int j = 0; j < 4; ++j) {
            acc.x += v[j].x; acc.y += v[j].y; acc.z += v[j].z; acc.w += v[j].w;
            O4[vb4 + (size_t)(row0 + j) * 16 + col4] = acc;
        }
    } else {
        // ----- radix top-40 (8 bits/pass, 4 passes); then sort desc by index.
        int bh = blockIdx.x - 1024;
        __shared__ unsigned hist[256];
        __shared__ unsigned bc_prefix, bc_need;
        __shared__ unsigned cnt_gt, cnt_eq;
        __shared__ int eqlist[128];
        __shared__ int sel[SK];

        unsigned v[8];
        #pragma unroll
        for (int j = 0; j < 8; ++j)
            v[j] = ordu(M[(size_t)bh * LL + tid + j * 256]);

        unsigned prefix = 0, need = SK;
        #pragma unroll
        for (int pass = 0; pass < 4; ++pass) {
            const int s = 24 - 8 * pass;
            const unsigned maskHigh = (pass == 0) ? 0u : (0xFFFFFFFFu << (s + 8));
            hist[tid] = 0;
            __syncthreads();
            #pragma unroll
            for (int j = 0; j < 8; ++j)
                if (((v[j] ^ prefix) & maskHigh) == 0)
                    atomicAdd(&hist[(v[j] >> s) & 0xFF], 1u);
            __syncthreads();
            unsigned above = 0;
            for (int b = tid + 1; b < 256; ++b) above += hist[b];
            if (above < need && above + hist[tid] >= need) {
                bc_prefix = prefix | ((unsigned)tid << s);
                bc_need = need - above;
            }
            __syncthreads();
            prefix = bc_prefix;
            need = bc_need;
            __syncthreads();
        }
        unsigned T = prefix;
        if (tid == 0) { cnt_gt = 0; cnt_eq = 0; }
        __syncthreads();
        #pragma unroll
        for (int j = 0; j < 8; ++j) {
            int idx = tid + j * 256;
            if (v[j] > T) { unsigned p = atomicAdd(&cnt_gt, 1u); sel[p] = idx; }
            else if (v[j] == T) { unsigned p = atomicAdd(&cnt_eq, 1u); if (p < 128) eqlist[p] = idx; }
        }
        __syncthreads();
        if (tid == 0) {
            int ne = (int)min(cnt_eq, 128u);
            unsigned base = cnt_gt;       // == SK - need
            for (unsigned r2 = 0; r2 < need; ++r2) {
                int bj = 0, bv = 0x7FFFFFFF;
                for (int j = 0; j < ne; ++j)
                    if (eqlist[j] < bv) { bv = eqlist[j]; bj = j; }
                sel[base + r2] = bv;
                eqlist[bj] = 0x7FFFFFFF;
            }
        }
        __syncthreads();
        // rank-sort descending by qpos (indices distinct): longest rows first
        if (tid < SK) {
            int mine = sel[tid];
            int rank = 0;
            #pragma unroll
            for (int j = 0; j < SK; ++j) rank += (sel[j] > mine);
            topk[bh * SK + rank] = mine;
        }
    }
}

// ---------------------------------------------------------------------------
// Stage 3: one block per (bh,u): full causal softmax attention over keys
// [0..qpos]. bh = x&31 (XCD spread), u = x>>5 (longest-first via sorted topk).
// R6-proven simple body (no manual prefetch).
__global__ __launch_bounds__(256) void attn_kernel(
        const float* __restrict__ Q, const float* __restrict__ K,
        const float* __restrict__ V, const int* __restrict__ topk,
        float* __restrict__ out) {
    int x = blockIdx.x;               // 1280
    int bh = x & 31;
    int u = x >> 5;
    int tid = threadIdx.x;

    int qpos = topk[bh * SK + u];
    int nk = qpos + 1;

    const float4* Q4 = (const float4*)Q;
    const float4* K4 = (const float4*)K;
    const float4* V4 = (const float4*)V;

    int w = tid >> 6, lane = tid & 63;
    int kw = lane >> 2, c = lane & 3;
    float4 qreg[4];
    #pragma unroll
    for (int j = 0; j < 4; ++j)
        qreg[j] = Q4[((size_t)bh * LL + qpos) * 16 + j * 4 + c];

    __shared__ float sc[LL];          // 8 KB
    __shared__ float red[4], red2[4];
    __shared__ float opart[16][16][4];

    // score phase: 4 lanes/key, 64 keys per block-round
    size_t kb4 = (size_t)bh * LL * 16;
    int rounds = (nk + 63) >> 6;
    for (int rr = 0; rr < rounds; ++rr) {
        int key = rr * 64 + w * 16 + kw;
        if (key < nk) {
            const float4* kr = K4 + kb4 + (size_t)key * 16;
            float p = dot4(kr[c], qreg[0]) + dot4(kr[4 + c], qreg[1])
                    + dot4(kr[8 + c], qreg[2]) + dot4(kr[12 + c], qreg[3]);
            p += __shfl_xor(p, 1, 64);
            p += __shfl_xor(p, 2, 64);
            if (c == 0) sc[key] = p * 0.125f;   // 1/sqrt(64)
        }
    }
    __syncthreads();

    // block max over sc[0..nk)
    float m = -INFINITY;
    for (int j = tid; j < nk; j += 256) m = fmaxf(m, sc[j]);
    #pragma unroll
    for (int off = 32; off > 0; off >>= 1) m = fmaxf(m, __shfl_xor(m, off, 64));
    if (lane == 0) red[w] = m;
    __syncthreads();
    m = fmaxf(fmaxf(red[0], red[1]), fmaxf(red[2], red[3]));

    // exp + block sum
    float ls = 0.f;
    for (int j = tid; j < nk; j += 256) {
        float e = expf(sc[j] - m);
        sc[j] = e;
        ls += e;
    }
    #pragma unroll
    for (int off = 32; off > 0; off >>= 1) ls += __shfl_xor(ls, off, 64);
    if (lane == 0) red2[w] = ls;
    __syncthreads();
    float linv = 1.0f / (red2[0] + red2[1] + red2[2] + red2[3]);

    // weighted V: 16 k-groups x 16 float4 columns
    int col4 = tid & 15, kg = tid >> 4;
    float ax = 0.f, ay = 0.f, az = 0.f, aw = 0.f;
    size_t vb4 = (size_t)bh * LL * 16;
    for (int j = kg; j < nk; j += 16) {
        float sj = sc[j];
        float4 vv = V4[vb4 + (size_t)j * 16 + col4];
        ax += sj * vv.x; ay += sj * vv.y; az += sj * vv.z; aw += sj * vv.w;
    }
    opart[kg][col4][0] = ax;
    opart[kg][col4][1] = ay;
    opart[kg][col4][2] = az;
    opart[kg][col4][3] = aw;
    __syncthreads();
    if (tid < DD) {
        int c4 = tid >> 2, cp = tid & 3;
        float s = 0.f;
        #pragma unroll
        for (int kg2 = 0; kg2 < 16; ++kg2) s += opart[kg2][c4][cp];
        out[((size_t)bh * LL + qpos) * DD + tid] = s * linv;
    }
}

// ---------------------------------------------------------------------------
extern "C" void kernel_launch(void* const* d_in, const int* in_sizes, int n_in,
                              void* d_out, int out_size, void* d_ws, size_t ws_size,
                              hipStream_t stream) {
    const float* Q   = (const float*)d_in[0];
    const float* K   = (const float*)d_in[1];
    const float* V   = (const float*)d_in[2];
    const int*   IDX = (const int*)d_in[3];
    float* out = (float*)d_out;

    char* ws = (char*)d_ws;
    float* M    = (float*)ws;  ws += (size_t)BH * LL * sizeof(float);                 // 256 KB
    int*   topk = (int*)ws;    ws += ((size_t)BH * SK * sizeof(int) + 255) & ~255ull;
    float* csum = (float*)ws;  // BH*NC*64 floats = 256 KB

    stage1_kernel<<<2048, 256, 0, stream>>>(Q, K, V, IDX, M, csum);
    stage2_kernel<<<1056, 256, 0, stream>>>(V, csum, M, out, topk);
    attn_kernel<<<BH * SK, 256, 0, stream>>>(Q, K, V, topk, out);
}